// Round 1
// baseline (1654.003 us; speedup 1.0000x reference)
//
#include <hip/hip_runtime.h>

#define DIMN 8192
#define SEQ  1024
#define NHEAD 128

typedef __attribute__((ext_vector_type(8))) short bf16x8;
typedef __attribute__((ext_vector_type(4))) float f32x4;

#define MFMA16(a, b, c) __builtin_amdgcn_mfma_f32_16x16x32_bf16((a), (b), (c), 0, 0, 0)

__device__ __forceinline__ unsigned short f2bf(float f) {
  unsigned u = __float_as_uint(f);
  return (unsigned short)((u + 0x7FFFu + ((u >> 16) & 1u)) >> 16);
}
__device__ __forceinline__ unsigned pack2(float a, float b) {
  return (unsigned)f2bf(a) | ((unsigned)f2bf(b) << 16);
}
__device__ __forceinline__ void async_copy16(void* lds_dst, const void* gsrc) {
  __builtin_amdgcn_global_load_lds(
      (const __attribute__((address_space(1))) unsigned int*)gsrc,
      (__attribute__((address_space(3))) unsigned int*)lds_dst, 16, 0, 0);
}

// ---------------- fp32 -> bf16 convert (x) ----------------
__global__ __launch_bounds__(256) void cvt_bf16_kernel(
    const float* __restrict__ in, unsigned short* __restrict__ out) {
  int i = blockIdx.x * 256 + threadIdx.x;   // 1,048,576 threads * 8 elems
  const float4* p = (const float4*)in;
  float4 a = p[2 * i];
  float4 b = p[2 * i + 1];
  uint4 r;
  r.x = pack2(a.x, a.y);
  r.y = pack2(a.z, a.w);
  r.z = pack2(b.x, b.y);
  r.w = pack2(b.z, b.w);
  ((uint4*)out)[i] = r;
}

// ---------------- GEMM: C[1024,8192] = A(bf16)[1024,8192] @ W(f32->bf16)[8192,8192] ----
// 128x128 tile, BK=64, 256 threads = 4 waves (2x2), mfma 16x16x32 bf16.
// A staged via global_load_lds (pre-swizzled source, linear LDS dest).
// B staged via reg (fp32 load -> cvt -> swizzled ds_write_b128), issue-early/write-late.
template <int WRITE_F32>
__global__ __launch_bounds__(256, 2) void gemm_bf16(
    const unsigned short* __restrict__ A, const float* __restrict__ W,
    void* __restrict__ Cout, float out_scale) {
  __shared__ unsigned short smem[2 * 16384];  // per buf: A[128][64] + B_t[128][64]
  const int t = threadIdx.x;
  const int l = t & 63;
  const int w = t >> 6;
  const int wm = w >> 1, wn = w & 1;
  const int m0 = (blockIdx.x & 7) * 128;   // m fastest: 8 consecutive blocks share B panel
  const int n0 = (blockIdx.x >> 3) * 128;

  // A staging geometry: one gload_lds = 8 rows x 8 slots(16B)
  const int rin = l >> 3;                  // row-in-group 0..7
  const int aslot = (l & 7) ^ rin;         // pre-swizzled source slot
  // B staging geometry
  const int bn = t & 127;                  // output col within tile
  const int bkb = (t >> 7) * 32;           // k base (0 or 32)

  f32x4 acc[4][4];
#pragma unroll
  for (int mb = 0; mb < 4; ++mb)
#pragma unroll
    for (int nb = 0; nb < 4; ++nb) acc[mb][nb] = (f32x4){0.f, 0.f, 0.f, 0.f};

  float fb[32];

  auto load_B = [&](int kt) {
    const float* wp = W + (size_t)(kt * 64 + bkb) * DIMN + n0 + bn;
#pragma unroll
    for (int i = 0; i < 32; ++i) fb[i] = wp[(size_t)i * DIMN];
  };
  auto write_B = [&](int buf) {
    unsigned short* bb = &smem[buf * 16384 + 8192];
#pragma unroll
    for (int j = 0; j < 4; ++j) {
      int p = ((bkb >> 3) + j) ^ (bn & 7);  // physical slot
      uint4 val;
      val.x = pack2(fb[j * 8 + 0], fb[j * 8 + 1]);
      val.y = pack2(fb[j * 8 + 2], fb[j * 8 + 3]);
      val.z = pack2(fb[j * 8 + 4], fb[j * 8 + 5]);
      val.w = pack2(fb[j * 8 + 6], fb[j * 8 + 7]);
      *(uint4*)&bb[bn * 64 + p * 8] = val;
    }
  };
  auto stage_A = [&](int buf, int kt) {
#pragma unroll
    for (int i = 0; i < 4; ++i) {
      int row = w * 32 + i * 8 + rin;
      const unsigned short* g = A + (size_t)(m0 + row) * DIMN + kt * 64 + aslot * 8;
      async_copy16(&smem[buf * 16384 + (w * 32 + i * 8) * 64], g);
    }
  };
  auto compute = [&](int buf) {
    const unsigned short* la = &smem[buf * 16384];
    const unsigned short* lb = la + 8192;
#pragma unroll
    for (int kh = 0; kh < 2; ++kh) {
      bf16x8 af[4], bfr[4];
#pragma unroll
      for (int mb = 0; mb < 4; ++mb) {
        int row = wm * 64 + mb * 16 + (l & 15);
        int sl = ((l >> 4) + kh * 4) ^ (row & 7);
        af[mb] = *(const bf16x8*)&la[row * 64 + sl * 8];
      }
#pragma unroll
      for (int nb = 0; nb < 4; ++nb) {
        int row = wn * 64 + nb * 16 + (l & 15);
        int sl = ((l >> 4) + kh * 4) ^ (row & 7);
        bfr[nb] = *(const bf16x8*)&lb[row * 64 + sl * 8];
      }
#pragma unroll
      for (int mb = 0; mb < 4; ++mb)
#pragma unroll
        for (int nb = 0; nb < 4; ++nb)
          acc[mb][nb] = MFMA16(af[mb], bfr[nb], acc[mb][nb]);
    }
  };

  // prologue
  load_B(0);
  stage_A(0, 0);
  write_B(0);
  __syncthreads();

  int buf = 0;
  for (int kt = 0; kt < 128; ++kt) {
    if (kt < 127) {
      load_B(kt + 1);        // issue global loads early (hide under MFMA)
      stage_A(buf ^ 1, kt + 1);
    }
    compute(buf);
    if (kt < 127) write_B(buf ^ 1);  // write-late into other buffer
    __syncthreads();
    buf ^= 1;
  }

  // epilogue: D layout col=lane&15, row=(lane>>4)*4+reg (m89-verified)
#pragma unroll
  for (int mb = 0; mb < 4; ++mb)
#pragma unroll
    for (int nb = 0; nb < 4; ++nb)
#pragma unroll
      for (int r = 0; r < 4; ++r) {
        int rg = m0 + wm * 64 + mb * 16 + (l >> 4) * 4 + r;
        int cg = n0 + wn * 64 + nb * 16 + (l & 15);
        float vl = acc[mb][nb][r] * out_scale;
        if (WRITE_F32)
          ((float*)Cout)[(size_t)rg * DIMN + cg] = vl;
        else
          ((unsigned short*)Cout)[(size_t)rg * DIMN + cg] = f2bf(vl);
      }
}

// ---------------- fused flash attention ----------------
// grid = 128 heads * 16 q-tiles; block = 256 thr (4 waves, 16 q-rows each).
// K/V tiles of 64 keys; padded LDS rows (72 bf16 = 144B) -> conflict-free ds_read_b128.
// Q pre-scaled by 0.125 in the Q-GEMM epilogue.
__global__ __launch_bounds__(256) void attn_kernel(
    const unsigned short* __restrict__ q, const unsigned short* __restrict__ k,
    const unsigned short* __restrict__ v, unsigned short* __restrict__ o) {
  __shared__ unsigned short Qs[64 * 72];
  __shared__ unsigned short Ks[64 * 72];
  __shared__ unsigned short Vt[64 * 72];
  __shared__ unsigned short Ps[4][16 * 72];

  const int t = threadIdx.x, l = t & 63, w = t >> 6;
  const int h = blockIdx.x >> 4;
  const int q0 = (blockIdx.x & 15) * 64;
  const int skey = t >> 2;        // 0..63
  const int sd = (t & 3) * 16;    // 0,16,32,48

  {  // stage Q tile [64 rows][64 d]
    const unsigned short* src = q + (size_t)(q0 + skey) * DIMN + h * 64 + sd;
    uint4 a = *(const uint4*)src;
    uint4 b = *(const uint4*)(src + 8);
    *(uint4*)&Qs[skey * 72 + sd] = a;
    *(uint4*)&Qs[skey * 72 + sd + 8] = b;
  }
  __syncthreads();
  bf16x8 qf[2];
#pragma unroll
  for (int kh = 0; kh < 2; ++kh)
    qf[kh] = *(const bf16x8*)&Qs[(w * 16 + (l & 15)) * 72 + (l >> 4) * 8 + kh * 32];

  float m_run[4] = {-1e30f, -1e30f, -1e30f, -1e30f};
  float l_run[4] = {0.f, 0.f, 0.f, 0.f};
  f32x4 oacc[4];
#pragma unroll
  for (int db = 0; db < 4; ++db) oacc[db] = (f32x4){0.f, 0.f, 0.f, 0.f};

  for (int kv = 0; kv < 16; ++kv) {
    __syncthreads();  // previous tile's MFMA reads done before overwrite
    {  // stage K tile + transposed V tile
      const unsigned short* ksrc = k + (size_t)(kv * 64 + skey) * DIMN + h * 64 + sd;
      uint4 a = *(const uint4*)ksrc;
      uint4 b = *(const uint4*)(ksrc + 8);
      *(uint4*)&Ks[skey * 72 + sd] = a;
      *(uint4*)&Ks[skey * 72 + sd + 8] = b;
      const unsigned short* vsrc = v + (size_t)(kv * 64 + skey) * DIMN + h * 64 + sd;
      uint4 c = *(const uint4*)vsrc;
      uint4 d = *(const uint4*)(vsrc + 8);
      const unsigned short* cs = (const unsigned short*)&c;
      const unsigned short* ds = (const unsigned short*)&d;
#pragma unroll
      for (int j = 0; j < 8; ++j) Vt[(sd + j) * 72 + skey] = cs[j];
#pragma unroll
      for (int j = 0; j < 8; ++j) Vt[(sd + 8 + j) * 72 + skey] = ds[j];
    }
    __syncthreads();

    // S = Q K^T (per wave: 16 q-rows x 64 keys)
    f32x4 sAcc[4];
#pragma unroll
    for (int nb = 0; nb < 4; ++nb) sAcc[nb] = (f32x4){0.f, 0.f, 0.f, 0.f};
#pragma unroll
    for (int kh = 0; kh < 2; ++kh) {
#pragma unroll
      for (int nb = 0; nb < 4; ++nb) {
        bf16x8 kf = *(const bf16x8*)&Ks[(nb * 16 + (l & 15)) * 72 + (l >> 4) * 8 + kh * 32];
        sAcc[nb] = MFMA16(qf[kh], kf, sAcc[nb]);
      }
    }

    // online softmax; lane owns rows (l>>4)*4+r, cols l&15 (+16*nb)
    float sc[4], mx[4];
#pragma unroll
    for (int r = 0; r < 4; ++r) {
      float mv = fmaxf(fmaxf(sAcc[0][r], sAcc[1][r]), fmaxf(sAcc[2][r], sAcc[3][r]));
      mv = fmaxf(mv, __shfl_xor(mv, 1));
      mv = fmaxf(mv, __shfl_xor(mv, 2));
      mv = fmaxf(mv, __shfl_xor(mv, 4));
      mv = fmaxf(mv, __shfl_xor(mv, 8));
      float mn = fmaxf(m_run[r], mv);
      sc[r] = __expf(m_run[r] - mn);
      m_run[r] = mn;
      mx[r] = mn;
    }
#pragma unroll
    for (int nb = 0; nb < 4; ++nb) {
      f32x4 sv = sAcc[nb];
#pragma unroll
      for (int r = 0; r < 4; ++r) sv[r] = __expf(sv[r] - mx[r]);
      sAcc[nb] = sv;
    }
#pragma unroll
    for (int r = 0; r < 4; ++r) {
      float ls = sAcc[0][r] + sAcc[1][r] + sAcc[2][r] + sAcc[3][r];
      ls += __shfl_xor(ls, 1);
      ls += __shfl_xor(ls, 2);
      ls += __shfl_xor(ls, 4);
      ls += __shfl_xor(ls, 8);
      l_run[r] = l_run[r] * sc[r] + ls;
    }
#pragma unroll
    for (int db = 0; db < 4; ++db) {
      f32x4 ov = oacc[db];
#pragma unroll
      for (int r = 0; r < 4; ++r) ov[r] *= sc[r];
      oacc[db] = ov;
    }

    // P -> bf16 -> per-wave LDS region [16 q][64 key]
#pragma unroll
    for (int nb = 0; nb < 4; ++nb)
#pragma unroll
      for (int r = 0; r < 4; ++r)
        Ps[w][((l >> 4) * 4 + r) * 72 + nb * 16 + (l & 15)] = f2bf(sAcc[nb][r]);

    // O += P V   (same-wave ds_write->ds_read, DS pipe is in-order per wave)
#pragma unroll
    for (int kh = 0; kh < 2; ++kh) {
      bf16x8 pf = *(const bf16x8*)&Ps[w][(l & 15) * 72 + (l >> 4) * 8 + kh * 32];
#pragma unroll
      for (int db = 0; db < 4; ++db) {
        bf16x8 vf = *(const bf16x8*)&Vt[(db * 16 + (l & 15)) * 72 + (l >> 4) * 8 + kh * 32];
        oacc[db] = MFMA16(pf, vf, oacc[db]);
      }
    }
  }

  // epilogue
#pragma unroll
  for (int db = 0; db < 4; ++db)
#pragma unroll
    for (int r = 0; r < 4; ++r) {
      float vl = oacc[db][r] / l_run[r];
      int rg = q0 + w * 16 + (l >> 4) * 4 + r;
      int cg = h * 64 + db * 16 + (l & 15);
      o[(size_t)rg * DIMN + cg] = f2bf(vl);
    }
}

extern "C" void kernel_launch(void* const* d_in, const int* in_sizes, int n_in,
                              void* d_out, int out_size, void* d_ws, size_t ws_size,
                              hipStream_t stream) {
  const float* x  = (const float*)d_in[0];
  const float* wq = (const float*)d_in[1];
  const float* wk = (const float*)d_in[2];
  const float* wv = (const float*)d_in[3];
  const float* wo = (const float*)d_in[4];

  char* ws = (char*)d_ws;
  const size_t MB16 = (size_t)16 * 1024 * 1024;
  unsigned short* xb = (unsigned short*)(ws);
  unsigned short* qb = (unsigned short*)(ws + 1 * MB16);
  unsigned short* kb = (unsigned short*)(ws + 2 * MB16);
  unsigned short* vb = (unsigned short*)(ws + 3 * MB16);
  unsigned short* ab = (unsigned short*)(ws + 4 * MB16);

  cvt_bf16_kernel<<<4096, 256, 0, stream>>>(x, xb);
  gemm_bf16<0><<<512, 256, 0, stream>>>(xb, wq, qb, 0.125f);  // softmax scale folded (exact pow2)
  gemm_bf16<0><<<512, 256, 0, stream>>>(xb, wk, kb, 1.0f);
  gemm_bf16<0><<<512, 256, 0, stream>>>(xb, wv, vb, 1.0f);
  attn_kernel<<<2048, 256, 0, stream>>>(qb, kb, vb, ab);
  gemm_bf16<1><<<512, 256, 0, stream>>>(ab, wo, d_out, 1.0f);
}

// Round 2
// 1349.580 us; speedup vs baseline: 1.2256x; 1.2256x over previous
//
#include <hip/hip_runtime.h>

#define DIMN 8192
#define SEQ  1024
#define NHEAD 128

typedef __attribute__((ext_vector_type(8))) short bf16x8;
typedef __attribute__((ext_vector_type(4))) float f32x4;

#define MFMA16(a, b, c) __builtin_amdgcn_mfma_f32_16x16x32_bf16((a), (b), (c), 0, 0, 0)

__device__ __forceinline__ unsigned short f2bf(float f) {
  unsigned u = __float_as_uint(f);
  return (unsigned short)((u + 0x7FFFu + ((u >> 16) & 1u)) >> 16);
}
__device__ __forceinline__ unsigned pack2(float a, float b) {
  return (unsigned)f2bf(a) | ((unsigned)f2bf(b) << 16);
}
__device__ __forceinline__ void async_copy16(void* lds_dst, const void* gsrc) {
  __builtin_amdgcn_global_load_lds(
      (const __attribute__((address_space(1))) unsigned int*)gsrc,
      (__attribute__((address_space(3))) unsigned int*)lds_dst, 16, 0, 0);
}

// ---------------- fp32 -> bf16 convert (x) ----------------
__global__ __launch_bounds__(256) void cvt_bf16_kernel(
    const float* __restrict__ in, unsigned short* __restrict__ out) {
  int i = blockIdx.x * 256 + threadIdx.x;   // 1,048,576 threads * 8 elems
  const float4* p = (const float4*)in;
  float4 a = p[2 * i];
  float4 b = p[2 * i + 1];
  uint4 r;
  r.x = pack2(a.x, a.y);
  r.y = pack2(a.z, a.w);
  r.z = pack2(b.x, b.y);
  r.w = pack2(b.z, b.w);
  ((uint4*)out)[i] = r;
}

// ---------------- GEMM: C[1024,8192] = A(bf16)[1024,8192] @ W(f32->bf16)[8192,8192] ----
// 128x128 tile, BK=64, 256 threads = 4 waves (2x2), mfma 16x16x32 bf16.
// A staged via global_load_lds (pre-swizzled source, linear LDS dest).
// B staged via reg (fp32 load -> cvt -> swizzled ds_write_b128), issue-early/write-late.
// XCD swizzle: 512 blocks, 8 XCDs, 2 blocks/CU -> all co-resident. Remap so
// XCD x owns logical blocks [x*64, x*64+64) = n-panels [x*8, x*8+8) with ALL
// 8 m-blocks of each panel on the same XCD -> each 32KB W k-slab fetched once
// per XCD into L2, served to the other 7 sharers (was: 8 XCDs each re-fetching).
template <int WRITE_F32>
__global__ __launch_bounds__(256, 2) void gemm_bf16(
    const unsigned short* __restrict__ A, const float* __restrict__ W,
    void* __restrict__ Cout, float out_scale) {
  __shared__ unsigned short smem[2 * 16384];  // per buf: A[128][64] + B_t[128][64]
  const int t = threadIdx.x;
  const int l = t & 63;
  const int w = t >> 6;
  const int wm = w >> 1, wn = w & 1;
  // XCD-aware remap (nwg=512, 8 XCDs, hardware round-robin blockIdx%8 -> XCD)
  const int logical = (blockIdx.x & 7) * 64 + (blockIdx.x >> 3);
  const int m0 = (logical & 7) * 128;   // m fastest within an XCD's chunk
  const int n0 = (logical >> 3) * 128;

  // A staging geometry: one gload_lds = 8 rows x 8 slots(16B)
  const int rin = l >> 3;                  // row-in-group 0..7
  const int aslot = (l & 7) ^ rin;         // pre-swizzled source slot
  // B staging geometry
  const int bn = t & 127;                  // output col within tile
  const int bkb = (t >> 7) * 32;           // k base (0 or 32)

  f32x4 acc[4][4];
#pragma unroll
  for (int mb = 0; mb < 4; ++mb)
#pragma unroll
    for (int nb = 0; nb < 4; ++nb) acc[mb][nb] = (f32x4){0.f, 0.f, 0.f, 0.f};

  float fb[32];

  auto load_B = [&](int kt) {
    const float* wp = W + (size_t)(kt * 64 + bkb) * DIMN + n0 + bn;
#pragma unroll
    for (int i = 0; i < 32; ++i) fb[i] = wp[(size_t)i * DIMN];
  };
  auto write_B = [&](int buf) {
    unsigned short* bb = &smem[buf * 16384 + 8192];
#pragma unroll
    for (int j = 0; j < 4; ++j) {
      int p = ((bkb >> 3) + j) ^ (bn & 7);  // physical slot
      uint4 val;
      val.x = pack2(fb[j * 8 + 0], fb[j * 8 + 1]);
      val.y = pack2(fb[j * 8 + 2], fb[j * 8 + 3]);
      val.z = pack2(fb[j * 8 + 4], fb[j * 8 + 5]);
      val.w = pack2(fb[j * 8 + 6], fb[j * 8 + 7]);
      *(uint4*)&bb[bn * 64 + p * 8] = val;
    }
  };
  auto stage_A = [&](int buf, int kt) {
#pragma unroll
    for (int i = 0; i < 4; ++i) {
      int row = w * 32 + i * 8 + rin;
      const unsigned short* g = A + (size_t)(m0 + row) * DIMN + kt * 64 + aslot * 8;
      async_copy16(&smem[buf * 16384 + (w * 32 + i * 8) * 64], g);
    }
  };
  auto compute = [&](int buf) {
    const unsigned short* la = &smem[buf * 16384];
    const unsigned short* lb = la + 8192;
#pragma unroll
    for (int kh = 0; kh < 2; ++kh) {
      bf16x8 af[4], bfr[4];
#pragma unroll
      for (int mb = 0; mb < 4; ++mb) {
        int row = wm * 64 + mb * 16 + (l & 15);
        int sl = ((l >> 4) + kh * 4) ^ (row & 7);
        af[mb] = *(const bf16x8*)&la[row * 64 + sl * 8];
      }
#pragma unroll
      for (int nb = 0; nb < 4; ++nb) {
        int row = wn * 64 + nb * 16 + (l & 15);
        int sl = ((l >> 4) + kh * 4) ^ (row & 7);
        bfr[nb] = *(const bf16x8*)&lb[row * 64 + sl * 8];
      }
#pragma unroll
      for (int mb = 0; mb < 4; ++mb)
#pragma unroll
        for (int nb = 0; nb < 4; ++nb)
          acc[mb][nb] = MFMA16(af[mb], bfr[nb], acc[mb][nb]);
    }
  };

  // prologue
  load_B(0);
  stage_A(0, 0);
  write_B(0);
  __syncthreads();

  int buf = 0;
  for (int kt = 0; kt < 128; ++kt) {
    if (kt < 127) {
      load_B(kt + 1);        // issue global loads early (hide under MFMA)
      stage_A(buf ^ 1, kt + 1);
    }
    compute(buf);
    if (kt < 127) write_B(buf ^ 1);  // write-late into other buffer
    __syncthreads();
    buf ^= 1;
  }

  // epilogue: D layout col=lane&15, row=(lane>>4)*4+reg (m89-verified)
#pragma unroll
  for (int mb = 0; mb < 4; ++mb)
#pragma unroll
    for (int nb = 0; nb < 4; ++nb)
#pragma unroll
      for (int r = 0; r < 4; ++r) {
        int rg = m0 + wm * 64 + mb * 16 + (l >> 4) * 4 + r;
        int cg = n0 + wn * 64 + nb * 16 + (l & 15);
        float vl = acc[mb][nb][r] * out_scale;
        if (WRITE_F32)
          ((float*)Cout)[(size_t)rg * DIMN + cg] = vl;
        else
          ((unsigned short*)Cout)[(size_t)rg * DIMN + cg] = f2bf(vl);
      }
}

// ---------------- fused flash attention ----------------
// grid = 128 heads * 16 q-tiles; block = 256 thr (4 waves, 16 q-rows each).
// K/V tiles of 64 keys; padded LDS rows (72 bf16 = 144B) -> conflict-free ds_read_b128.
// Q pre-scaled by 0.125 in the Q-GEMM epilogue.
__global__ __launch_bounds__(256) void attn_kernel(
    const unsigned short* __restrict__ q, const unsigned short* __restrict__ k,
    const unsigned short* __restrict__ v, unsigned short* __restrict__ o) {
  __shared__ unsigned short Qs[64 * 72];
  __shared__ unsigned short Ks[64 * 72];
  __shared__ unsigned short Vt[64 * 72];
  __shared__ unsigned short Ps[4][16 * 72];

  const int t = threadIdx.x, l = t & 63, w = t >> 6;
  const int h = blockIdx.x >> 4;
  const int q0 = (blockIdx.x & 15) * 64;
  const int skey = t >> 2;        // 0..63
  const int sd = (t & 3) * 16;    // 0,16,32,48

  {  // stage Q tile [64 rows][64 d]
    const unsigned short* src = q + (size_t)(q0 + skey) * DIMN + h * 64 + sd;
    uint4 a = *(const uint4*)src;
    uint4 b = *(const uint4*)(src + 8);
    *(uint4*)&Qs[skey * 72 + sd] = a;
    *(uint4*)&Qs[skey * 72 + sd + 8] = b;
  }
  __syncthreads();
  bf16x8 qf[2];
#pragma unroll
  for (int kh = 0; kh < 2; ++kh)
    qf[kh] = *(const bf16x8*)&Qs[(w * 16 + (l & 15)) * 72 + (l >> 4) * 8 + kh * 32];

  float m_run[4] = {-1e30f, -1e30f, -1e30f, -1e30f};
  float l_run[4] = {0.f, 0.f, 0.f, 0.f};
  f32x4 oacc[4];
#pragma unroll
  for (int db = 0; db < 4; ++db) oacc[db] = (f32x4){0.f, 0.f, 0.f, 0.f};

  for (int kv = 0; kv < 16; ++kv) {
    __syncthreads();  // previous tile's MFMA reads done before overwrite
    {  // stage K tile + transposed V tile
      const unsigned short* ksrc = k + (size_t)(kv * 64 + skey) * DIMN + h * 64 + sd;
      uint4 a = *(const uint4*)ksrc;
      uint4 b = *(const uint4*)(ksrc + 8);
      *(uint4*)&Ks[skey * 72 + sd] = a;
      *(uint4*)&Ks[skey * 72 + sd + 8] = b;
      const unsigned short* vsrc = v + (size_t)(kv * 64 + skey) * DIMN + h * 64 + sd;
      uint4 c = *(const uint4*)vsrc;
      uint4 d = *(const uint4*)(vsrc + 8);
      const unsigned short* cs = (const unsigned short*)&c;
      const unsigned short* ds = (const unsigned short*)&d;
#pragma unroll
      for (int j = 0; j < 8; ++j) Vt[(sd + j) * 72 + skey] = cs[j];
#pragma unroll
      for (int j = 0; j < 8; ++j) Vt[(sd + 8 + j) * 72 + skey] = ds[j];
    }
    __syncthreads();

    // S = Q K^T (per wave: 16 q-rows x 64 keys)
    f32x4 sAcc[4];
#pragma unroll
    for (int nb = 0; nb < 4; ++nb) sAcc[nb] = (f32x4){0.f, 0.f, 0.f, 0.f};
#pragma unroll
    for (int kh = 0; kh < 2; ++kh) {
#pragma unroll
      for (int nb = 0; nb < 4; ++nb) {
        bf16x8 kf = *(const bf16x8*)&Ks[(nb * 16 + (l & 15)) * 72 + (l >> 4) * 8 + kh * 32];
        sAcc[nb] = MFMA16(qf[kh], kf, sAcc[nb]);
      }
    }

    // online softmax; lane owns rows (l>>4)*4+r, cols l&15 (+16*nb)
    float sc[4], mx[4];
#pragma unroll
    for (int r = 0; r < 4; ++r) {
      float mv = fmaxf(fmaxf(sAcc[0][r], sAcc[1][r]), fmaxf(sAcc[2][r], sAcc[3][r]));
      mv = fmaxf(mv, __shfl_xor(mv, 1));
      mv = fmaxf(mv, __shfl_xor(mv, 2));
      mv = fmaxf(mv, __shfl_xor(mv, 4));
      mv = fmaxf(mv, __shfl_xor(mv, 8));
      float mn = fmaxf(m_run[r], mv);
      sc[r] = __expf(m_run[r] - mn);
      m_run[r] = mn;
      mx[r] = mn;
    }
#pragma unroll
    for (int nb = 0; nb < 4; ++nb) {
      f32x4 sv = sAcc[nb];
#pragma unroll
      for (int r = 0; r < 4; ++r) sv[r] = __expf(sv[r] - mx[r]);
      sAcc[nb] = sv;
    }
#pragma unroll
    for (int r = 0; r < 4; ++r) {
      float ls = sAcc[0][r] + sAcc[1][r] + sAcc[2][r] + sAcc[3][r];
      ls += __shfl_xor(ls, 1);
      ls += __shfl_xor(ls, 2);
      ls += __shfl_xor(ls, 4);
      ls += __shfl_xor(ls, 8);
      l_run[r] = l_run[r] * sc[r] + ls;
    }
#pragma unroll
    for (int db = 0; db < 4; ++db) {
      f32x4 ov = oacc[db];
#pragma unroll
      for (int r = 0; r < 4; ++r) ov[r] *= sc[r];
      oacc[db] = ov;
    }

    // P -> bf16 -> per-wave LDS region [16 q][64 key]
#pragma unroll
    for (int nb = 0; nb < 4; ++nb)
#pragma unroll
      for (int r = 0; r < 4; ++r)
        Ps[w][((l >> 4) * 4 + r) * 72 + nb * 16 + (l & 15)] = f2bf(sAcc[nb][r]);

    // O += P V   (same-wave ds_write->ds_read, DS pipe is in-order per wave)
#pragma unroll
    for (int kh = 0; kh < 2; ++kh) {
      bf16x8 pf = *(const bf16x8*)&Ps[w][(l & 15) * 72 + (l >> 4) * 8 + kh * 32];
#pragma unroll
      for (int db = 0; db < 4; ++db) {
        bf16x8 vf = *(const bf16x8*)&Vt[(db * 16 + (l & 15)) * 72 + (l >> 4) * 8 + kh * 32];
        oacc[db] = MFMA16(pf, vf, oacc[db]);
      }
    }
  }

  // epilogue
#pragma unroll
  for (int db = 0; db < 4; ++db)
#pragma unroll
    for (int r = 0; r < 4; ++r) {
      float vl = oacc[db][r] / l_run[r];
      int rg = q0 + w * 16 + (l >> 4) * 4 + r;
      int cg = h * 64 + db * 16 + (l & 15);
      o[(size_t)rg * DIMN + cg] = f2bf(vl);
    }
}

extern "C" void kernel_launch(void* const* d_in, const int* in_sizes, int n_in,
                              void* d_out, int out_size, void* d_ws, size_t ws_size,
                              hipStream_t stream) {
  const float* x  = (const float*)d_in[0];
  const float* wq = (const float*)d_in[1];
  const float* wk = (const float*)d_in[2];
  const float* wv = (const float*)d_in[3];
  const float* wo = (const float*)d_in[4];

  char* ws = (char*)d_ws;
  const size_t MB16 = (size_t)16 * 1024 * 1024;
  unsigned short* xb = (unsigned short*)(ws);
  unsigned short* qb = (unsigned short*)(ws + 1 * MB16);
  unsigned short* kb = (unsigned short*)(ws + 2 * MB16);
  unsigned short* vb = (unsigned short*)(ws + 3 * MB16);
  unsigned short* ab = (unsigned short*)(ws + 4 * MB16);

  cvt_bf16_kernel<<<4096, 256, 0, stream>>>(x, xb);
  gemm_bf16<0><<<512, 256, 0, stream>>>(xb, wq, qb, 0.125f);  // softmax scale folded (exact pow2)
  gemm_bf16<0><<<512, 256, 0, stream>>>(xb, wk, kb, 1.0f);
  gemm_bf16<0><<<512, 256, 0, stream>>>(xb, wv, vb, 1.0f);
  attn_kernel<<<2048, 256, 0, stream>>>(qb, kb, vb, ab);
  gemm_bf16<1><<<512, 256, 0, stream>>>(ab, wo, d_out, 1.0f);
}

// Round 5
// 1151.752 us; speedup vs baseline: 1.4361x; 1.1718x over previous
//
#include <hip/hip_runtime.h>

#define DIMN 8192
#define SEQ  1024
#define NHEAD 128

typedef __attribute__((ext_vector_type(8))) short bf16x8;
typedef __attribute__((ext_vector_type(4))) float f32x4;

#define MFMA16(a, b, c) __builtin_amdgcn_mfma_f32_16x16x32_bf16((a), (b), (c), 0, 0, 0)

__device__ __forceinline__ unsigned short f2bf(float f) {
  unsigned u = __float_as_uint(f);
  return (unsigned short)((u + 0x7FFFu + ((u >> 16) & 1u)) >> 16);
}
__device__ __forceinline__ unsigned pack2(float a, float b) {
  return (unsigned)f2bf(a) | ((unsigned)f2bf(b) << 16);
}
// round-half-up bf16 pack: 4 VALU (2 add + lshr + and_or) vs ~10 for RNE pair.
// bias vs RNE is half-ULP ties only -> error magnitude unchanged.
__device__ __forceinline__ unsigned pack2_rhu(float lo, float hi) {
  unsigned a = __float_as_uint(lo) + 0x8000u;
  unsigned b = __float_as_uint(hi) + 0x8000u;
  return (a >> 16) | (b & 0xFFFF0000u);
}
__device__ __forceinline__ void async_copy16(void* lds_dst, const void* gsrc) {
  __builtin_amdgcn_global_load_lds(
      (const __attribute__((address_space(1))) unsigned int*)gsrc,
      (__attribute__((address_space(3))) unsigned int*)lds_dst, 16, 0, 0);
}

// ---------------- fp32 -> bf16 convert (x) ----------------
__global__ __launch_bounds__(256) void cvt_bf16_kernel(
    const float* __restrict__ in, unsigned short* __restrict__ out) {
  int i = blockIdx.x * 256 + threadIdx.x;   // 1,048,576 threads * 8 elems
  const float4* p = (const float4*)in;
  float4 a = p[2 * i];
  float4 b = p[2 * i + 1];
  uint4 r;
  r.x = pack2(a.x, a.y);
  r.y = pack2(a.z, a.w);
  r.z = pack2(b.x, b.y);
  r.w = pack2(b.z, b.w);
  ((uint4*)out)[i] = r;
}

// ---------------- GEMM: C[1024,8192] = A(bf16)[1024,8192] @ W(f32->bf16)[8192,8192] ----
// 128x256 tile, BK=64, 512 threads = 8 waves (2M x 4N, 64x64 out each),
// mfma 16x16x32 bf16, 32 MFMA/wave/K-tile. 96KB double-buffered LDS -> 1 block/CU,
// 2 waves/SIMD. A via global_load_lds (pre-swizzled source, linear dest, XOR slots).
// B reg-staged (fp32 load -> cheap pack -> swizzled ds_write_b128), issue-early/
// write-late so HBM/L2 latency hides under the 32-MFMA compute phase.
// XCD swizzle: 256 blocks = 1/CU; XCD x owns n-panels [4x, 4x+4), each with all
// 8 m-sharers co-resident on that XCD -> W k-slabs fetched once per XCD.
template <int WRITE_F32>
__global__ __launch_bounds__(512, 2) void gemm_bf16(
    const unsigned short* __restrict__ A, const float* __restrict__ W,
    void* __restrict__ Cout, float out_scale) {
  __shared__ unsigned short smem[2 * 24576];  // per buf: A[128][64] + B_t[256][64]
  const int t = threadIdx.x;
  const int l = t & 63;
  const int w = t >> 6;                 // 0..7
  const int wm = w >> 2, wn = w & 3;    // 2M x 4N wave grid
  const int logical = (blockIdx.x & 7) * 32 + (blockIdx.x >> 3);
  const int m0 = (logical & 7) * 128;   // m fastest within an XCD's chunk
  const int n0 = (logical >> 3) * 256;

  // A staging: per wave 2 gload_lds, each 8 rows x 8 slots(16B)
  const int rin = l >> 3;                  // row-in-group 0..7
  const int aslot = (l & 7) ^ rin;         // pre-swizzled source slot
  // B staging: thread owns col bn, k-rows [bkb, bkb+32)
  const int bn = t & 255;
  const int bkb = (t >> 8) * 32;

  f32x4 acc[4][4];
#pragma unroll
  for (int mb = 0; mb < 4; ++mb)
#pragma unroll
    for (int nb = 0; nb < 4; ++nb) acc[mb][nb] = (f32x4){0.f, 0.f, 0.f, 0.f};

  float fb[32];
  const unsigned short* aptr = A + (size_t)(m0 + w * 16 + rin) * DIMN + aslot * 8;
  const float* wp = W + (size_t)bkb * DIMN + n0 + bn;

  auto load_B = [&]() {
#pragma unroll
    for (int i = 0; i < 32; ++i) fb[i] = wp[(size_t)i * DIMN];
    wp += (size_t)64 * DIMN;
  };
  auto write_B = [&](int buf) {
    unsigned short* bb = &smem[buf * 24576 + 8192];
#pragma unroll
    for (int j = 0; j < 4; ++j) {
      int p = ((bkb >> 3) + j) ^ (bn & 7);  // physical slot (XOR swizzle)
      uint4 val;
      val.x = pack2_rhu(fb[j * 8 + 0], fb[j * 8 + 1]);
      val.y = pack2_rhu(fb[j * 8 + 2], fb[j * 8 + 3]);
      val.z = pack2_rhu(fb[j * 8 + 4], fb[j * 8 + 5]);
      val.w = pack2_rhu(fb[j * 8 + 6], fb[j * 8 + 7]);
      *(uint4*)&bb[bn * 64 + p * 8] = val;
    }
  };
  auto stage_A = [&](int buf) {
#pragma unroll
    for (int i = 0; i < 2; ++i)
      async_copy16(&smem[buf * 24576 + (w * 16 + i * 8) * 64], aptr + (size_t)i * 8 * DIMN);
    aptr += 64;
  };
  auto compute = [&](int buf) {
    const unsigned short* la = &smem[buf * 24576];
    const unsigned short* lb = la + 8192;
#pragma unroll
    for (int kh = 0; kh < 2; ++kh) {
      bf16x8 af[4], bfr[4];
#pragma unroll
      for (int mb = 0; mb < 4; ++mb) {
        int row = wm * 64 + mb * 16 + (l & 15);
        int sl = ((l >> 4) + kh * 4) ^ (row & 7);
        af[mb] = *(const bf16x8*)&la[row * 64 + sl * 8];
      }
#pragma unroll
      for (int nb = 0; nb < 4; ++nb) {
        int row = wn * 64 + nb * 16 + (l & 15);
        int sl = ((l >> 4) + kh * 4) ^ (row & 7);
        bfr[nb] = *(const bf16x8*)&lb[row * 64 + sl * 8];
      }
#pragma unroll
      for (int mb = 0; mb < 4; ++mb)
#pragma unroll
        for (int nb = 0; nb < 4; ++nb)
          acc[mb][nb] = MFMA16(af[mb], bfr[nb], acc[mb][nb]);
    }
  };

  // prologue: tile 0
  load_B();
  stage_A(0);
  write_B(0);
  __syncthreads();

  int buf = 0;
  for (int kt = 0; kt < 128; ++kt) {
    if (kt < 127) {
      load_B();            // issue next-tile B fp32 loads early (regs)
      stage_A(buf ^ 1);    // issue next-tile A gload_lds
    }
    compute(buf);          // 32 MFMA/wave hide the load latency
    if (kt < 127) write_B(buf ^ 1);  // cvt + LDS write after compute
    __syncthreads();
    buf ^= 1;
  }

  // epilogue: D layout col=lane&15, row=(lane>>4)*4+reg (m89-verified)
#pragma unroll
  for (int mb = 0; mb < 4; ++mb)
#pragma unroll
    for (int nb = 0; nb < 4; ++nb)
#pragma unroll
      for (int r = 0; r < 4; ++r) {
        int rg = m0 + wm * 64 + mb * 16 + (l >> 4) * 4 + r;
        int cg = n0 + wn * 64 + nb * 16 + (l & 15);
        float vl = acc[mb][nb][r] * out_scale;
        if (WRITE_F32)
          ((float*)Cout)[(size_t)rg * DIMN + cg] = vl;
        else
          ((unsigned short*)Cout)[(size_t)rg * DIMN + cg] = f2bf(vl);
      }
}

// ---------------- fused flash attention ----------------
// grid = 128 heads * 16 q-tiles; block = 256 thr (4 waves, 16 q-rows each).
// K/V tiles of 64 keys; padded LDS rows (72 bf16 = 144B) -> conflict-free ds_read_b128.
// Q pre-scaled by 0.125 in the Q-GEMM epilogue.
__global__ __launch_bounds__(256) void attn_kernel(
    const unsigned short* __restrict__ q, const unsigned short* __restrict__ k,
    const unsigned short* __restrict__ v, unsigned short* __restrict__ o) {
  __shared__ unsigned short Qs[64 * 72];
  __shared__ unsigned short Ks[64 * 72];
  __shared__ unsigned short Vt[64 * 72];
  __shared__ unsigned short Ps[4][16 * 72];

  const int t = threadIdx.x, l = t & 63, w = t >> 6;
  const int h = blockIdx.x >> 4;
  const int q0 = (blockIdx.x & 15) * 64;
  const int skey = t >> 2;        // 0..63
  const int sd = (t & 3) * 16;    // 0,16,32,48

  {  // stage Q tile [64 rows][64 d]
    const unsigned short* src = q + (size_t)(q0 + skey) * DIMN + h * 64 + sd;
    uint4 a = *(const uint4*)src;
    uint4 b = *(const uint4*)(src + 8);
    *(uint4*)&Qs[skey * 72 + sd] = a;
    *(uint4*)&Qs[skey * 72 + sd + 8] = b;
  }
  __syncthreads();
  bf16x8 qf[2];
#pragma unroll
  for (int kh = 0; kh < 2; ++kh)
    qf[kh] = *(const bf16x8*)&Qs[(w * 16 + (l & 15)) * 72 + (l >> 4) * 8 + kh * 32];

  float m_run[4] = {-1e30f, -1e30f, -1e30f, -1e30f};
  float l_run[4] = {0.f, 0.f, 0.f, 0.f};
  f32x4 oacc[4];
#pragma unroll
  for (int db = 0; db < 4; ++db) oacc[db] = (f32x4){0.f, 0.f, 0.f, 0.f};

  for (int kv = 0; kv < 16; ++kv) {
    __syncthreads();  // previous tile's MFMA reads done before overwrite
    {  // stage K tile + transposed V tile
      const unsigned short* ksrc = k + (size_t)(kv * 64 + skey) * DIMN + h * 64 + sd;
      uint4 a = *(const uint4*)ksrc;
      uint4 b = *(const uint4*)(ksrc + 8);
      *(uint4*)&Ks[skey * 72 + sd] = a;
      *(uint4*)&Ks[skey * 72 + sd + 8] = b;
      const unsigned short* vsrc = v + (size_t)(kv * 64 + skey) * DIMN + h * 64 + sd;
      uint4 c = *(const uint4*)vsrc;
      uint4 d = *(const uint4*)(vsrc + 8);
      const unsigned short* cs = (const unsigned short*)&c;
      const unsigned short* ds = (const unsigned short*)&d;
#pragma unroll
      for (int j = 0; j < 8; ++j) Vt[(sd + j) * 72 + skey] = cs[j];
#pragma unroll
      for (int j = 0; j < 8; ++j) Vt[(sd + 8 + j) * 72 + skey] = ds[j];
    }
    __syncthreads();

    // S = Q K^T (per wave: 16 q-rows x 64 keys)
    f32x4 sAcc[4];
#pragma unroll
    for (int nb = 0; nb < 4; ++nb) sAcc[nb] = (f32x4){0.f, 0.f, 0.f, 0.f};
#pragma unroll
    for (int kh = 0; kh < 2; ++kh) {
#pragma unroll
      for (int nb = 0; nb < 4; ++nb) {
        bf16x8 kf = *(const bf16x8*)&Ks[(nb * 16 + (l & 15)) * 72 + (l >> 4) * 8 + kh * 32];
        sAcc[nb] = MFMA16(qf[kh], kf, sAcc[nb]);
      }
    }

    // online softmax; lane owns rows (l>>4)*4+r, cols l&15 (+16*nb)
    float sc[4], mx[4];
#pragma unroll
    for (int r = 0; r < 4; ++r) {
      float mv = fmaxf(fmaxf(sAcc[0][r], sAcc[1][r]), fmaxf(sAcc[2][r], sAcc[3][r]));
      mv = fmaxf(mv, __shfl_xor(mv, 1));
      mv = fmaxf(mv, __shfl_xor(mv, 2));
      mv = fmaxf(mv, __shfl_xor(mv, 4));
      mv = fmaxf(mv, __shfl_xor(mv, 8));
      float mn = fmaxf(m_run[r], mv);
      sc[r] = __expf(m_run[r] - mn);
      m_run[r] = mn;
      mx[r] = mn;
    }
#pragma unroll
    for (int nb = 0; nb < 4; ++nb) {
      f32x4 sv = sAcc[nb];
#pragma unroll
      for (int r = 0; r < 4; ++r) sv[r] = __expf(sv[r] - mx[r]);
      sAcc[nb] = sv;
    }
#pragma unroll
    for (int r = 0; r < 4; ++r) {
      float ls = sAcc[0][r] + sAcc[1][r] + sAcc[2][r] + sAcc[3][r];
      ls += __shfl_xor(ls, 1);
      ls += __shfl_xor(ls, 2);
      ls += __shfl_xor(ls, 4);
      ls += __shfl_xor(ls, 8);
      l_run[r] = l_run[r] * sc[r] + ls;
    }
#pragma unroll
    for (int db = 0; db < 4; ++db) {
      f32x4 ov = oacc[db];
#pragma unroll
      for (int r = 0; r < 4; ++r) ov[r] *= sc[r];
      oacc[db] = ov;
    }

    // P -> bf16 -> per-wave LDS region [16 q][64 key]
#pragma unroll
    for (int nb = 0; nb < 4; ++nb)
#pragma unroll
      for (int r = 0; r < 4; ++r)
        Ps[w][((l >> 4) * 4 + r) * 72 + nb * 16 + (l & 15)] = f2bf(sAcc[nb][r]);

    // O += P V   (same-wave ds_write->ds_read, DS pipe is in-order per wave)
#pragma unroll
    for (int kh = 0; kh < 2; ++kh) {
      bf16x8 pf = *(const bf16x8*)&Ps[w][(l & 15) * 72 + (l >> 4) * 8 + kh * 32];
#pragma unroll
      for (int db = 0; db < 4; ++db) {
        bf16x8 vf = *(const bf16x8*)&Vt[(db * 16 + (l & 15)) * 72 + (l >> 4) * 8 + kh * 32];
        oacc[db] = MFMA16(pf, vf, oacc[db]);
      }
    }
  }

  // epilogue
#pragma unroll
  for (int db = 0; db < 4; ++db)
#pragma unroll
    for (int r = 0; r < 4; ++r) {
      float vl = oacc[db][r] / l_run[r];
      int rg = q0 + w * 16 + (l >> 4) * 4 + r;
      int cg = h * 64 + db * 16 + (l & 15);
      o[(size_t)rg * DIMN + cg] = f2bf(vl);
    }
}

extern "C" void kernel_launch(void* const* d_in, const int* in_sizes, int n_in,
                              void* d_out, int out_size, void* d_ws, size_t ws_size,
                              hipStream_t stream) {
  const float* x  = (const float*)d_in[0];
  const float* wq = (const float*)d_in[1];
  const float* wk = (const float*)d_in[2];
  const float* wv = (const float*)d_in[3];
  const float* wo = (const float*)d_in[4];

  char* ws = (char*)d_ws;
  const size_t MB16 = (size_t)16 * 1024 * 1024;
  unsigned short* xb = (unsigned short*)(ws);
  unsigned short* qb = (unsigned short*)(ws + 1 * MB16);
  unsigned short* kb = (unsigned short*)(ws + 2 * MB16);
  unsigned short* vb = (unsigned short*)(ws + 3 * MB16);
  unsigned short* ab = (unsigned short*)(ws + 4 * MB16);

  cvt_bf16_kernel<<<4096, 256, 0, stream>>>(x, xb);
  gemm_bf16<0><<<256, 512, 0, stream>>>(xb, wq, qb, 0.125f);  // softmax scale folded (exact pow2)
  gemm_bf16<0><<<256, 512, 0, stream>>>(xb, wk, kb, 1.0f);
  gemm_bf16<0><<<256, 512, 0, stream>>>(xb, wv, vb, 1.0f);
  attn_kernel<<<2048, 256, 0, stream>>>(qb, kb, vb, ab);
  gemm_bf16<1><<<256, 512, 0, stream>>>(ab, wo, d_out, 1.0f);
}

// Round 6
// 1075.809 us; speedup vs baseline: 1.5374x; 1.0706x over previous
//
#include <hip/hip_runtime.h>

#define DIMN 8192
#define SEQ  1024
#define NHEAD 128

typedef __attribute__((ext_vector_type(8))) short bf16x8;
typedef __attribute__((ext_vector_type(4))) float f32x4;

#define MFMA16(a, b, c) __builtin_amdgcn_mfma_f32_16x16x32_bf16((a), (b), (c), 0, 0, 0)

// counted waits + raw barrier (T4): never vmcnt(0) in the main loop
#define VMCNT2()  asm volatile("s_waitcnt vmcnt(2)" ::: "memory")
#define VMCNT0()  asm volatile("s_waitcnt vmcnt(0)" ::: "memory")
#define LGKM0()   asm volatile("s_waitcnt lgkmcnt(0)" ::: "memory")
#define BARRIER() do { __builtin_amdgcn_s_barrier(); __builtin_amdgcn_sched_barrier(0); } while (0)

__device__ __forceinline__ unsigned short f2bf(float f) {
  unsigned u = __float_as_uint(f);
  return (unsigned short)((u + 0x7FFFu + ((u >> 16) & 1u)) >> 16);
}
__device__ __forceinline__ unsigned pack2(float a, float b) {
  return (unsigned)f2bf(a) | ((unsigned)f2bf(b) << 16);
}
// round-half-up bf16 pack: 4 VALU vs ~10 for RNE pair (ties-only bias).
__device__ __forceinline__ unsigned pack2_rhu(float lo, float hi) {
  unsigned a = __float_as_uint(lo) + 0x8000u;
  unsigned b = __float_as_uint(hi) + 0x8000u;
  return (a >> 16) | (b & 0xFFFF0000u);
}
__device__ __forceinline__ void async_copy16(void* lds_dst, const void* gsrc) {
  __builtin_amdgcn_global_load_lds(
      (const __attribute__((address_space(1))) unsigned int*)gsrc,
      (__attribute__((address_space(3))) unsigned int*)lds_dst, 16, 0, 0);
}

// ---------------- fp32 -> bf16 convert (x) ----------------
__global__ __launch_bounds__(256) void cvt_bf16_kernel(
    const float* __restrict__ in, unsigned short* __restrict__ out) {
  int i = blockIdx.x * 256 + threadIdx.x;
  const float4* p = (const float4*)in;
  float4 a = p[2 * i];
  float4 b = p[2 * i + 1];
  uint4 r;
  r.x = pack2(a.x, a.y);
  r.y = pack2(a.z, a.w);
  r.z = pack2(b.x, b.y);
  r.w = pack2(b.z, b.w);
  ((uint4*)out)[i] = r;
}

// ---------------- GEMM: C[1024,8192] = A(bf16) @ W(f32->bf16) ----------------
// 128x256 tile, BK=64, 512 thr = 8 waves (2Mx4N, 64x64 out each), mfma 16x16x32.
// T4 pipeline: 3-deep LDS (144KB, 1 block/CU), raw s_barrier + counted vmcnt.
// Iter t: [lgkm0+barrier: tile t ready] -> issue B-loads(t+1) + A-gload_lds(t+2)
//         -> compute(t%3) (setprio around MFMA) -> vmcnt(2): B(t+1)&A(t+1) done,
//            A(t+2) stays in flight -> pack+ds_write B(t+1).
// Per-wave VMEM FIFO: [B(t+1) x32, A(t+2) x2] after issue; vmcnt(2) leaves A(t+2).
// A via gload_lds (pre-swizzled source, linear dest); B reg-staged fp32->bf16
// with XOR-swizzled ds_write (fused transpose). XCD swizzle as before.
template <int WRITE_F32>
__global__ __launch_bounds__(512, 2) void gemm_bf16(
    const unsigned short* __restrict__ A, const float* __restrict__ W,
    void* __restrict__ Cout, float out_scale) {
  __shared__ unsigned short smem[3 * 24576];  // per buf: A[128][64] + B_t[256][64]
  const int t = threadIdx.x;
  const int l = t & 63;
  const int w = t >> 6;
  const int wm = w >> 2, wn = w & 3;
  const int logical = (blockIdx.x & 7) * 32 + (blockIdx.x >> 3);
  const int m0 = (logical & 7) * 128;
  const int n0 = (logical >> 3) * 256;

  const int rin = l >> 3;
  const int aslot = (l & 7) ^ rin;
  const int bn = t & 255;
  const int bkb = (t >> 8) * 32;

  f32x4 acc[4][4];
#pragma unroll
  for (int mb = 0; mb < 4; ++mb)
#pragma unroll
    for (int nb = 0; nb < 4; ++nb) acc[mb][nb] = (f32x4){0.f, 0.f, 0.f, 0.f};

  float fb[32];
  const unsigned short* aptr = A + (size_t)(m0 + w * 16 + rin) * DIMN + aslot * 8;
  const float* wp = W + (size_t)bkb * DIMN + n0 + bn;

  auto load_B = [&]() {   // issue 32 fp32 loads (coalesced rows), advance ptr
#pragma unroll
    for (int i = 0; i < 32; ++i) fb[i] = wp[(size_t)i * DIMN];
    wp += (size_t)64 * DIMN;
  };
  auto write_B = [&](int buf) {   // buf is a literal at every call site
    unsigned short* bb = &smem[buf * 24576 + 8192];
#pragma unroll
    for (int j = 0; j < 4; ++j) {
      int p = ((bkb >> 3) + j) ^ (bn & 7);
      uint4 val;
      val.x = pack2_rhu(fb[j * 8 + 0], fb[j * 8 + 1]);
      val.y = pack2_rhu(fb[j * 8 + 2], fb[j * 8 + 3]);
      val.z = pack2_rhu(fb[j * 8 + 4], fb[j * 8 + 5]);
      val.w = pack2_rhu(fb[j * 8 + 6], fb[j * 8 + 7]);
      *(uint4*)&bb[bn * 64 + p * 8] = val;
    }
  };
  auto stage_A = [&](int buf) {   // 2 gload_lds, advance ptr
#pragma unroll
    for (int i = 0; i < 2; ++i)
      async_copy16(&smem[buf * 24576 + (w * 16 + i * 8) * 64], aptr + (size_t)i * 8 * DIMN);
    aptr += 64;
  };
  auto compute = [&](int buf) {
    const unsigned short* la = &smem[buf * 24576];
    const unsigned short* lb = la + 8192;
#pragma unroll
    for (int kh = 0; kh < 2; ++kh) {
      bf16x8 af[4], bfr[4];
#pragma unroll
      for (int mb = 0; mb < 4; ++mb) {
        int row = wm * 64 + mb * 16 + (l & 15);
        int sl = ((l >> 4) + kh * 4) ^ (row & 7);
        af[mb] = *(const bf16x8*)&la[row * 64 + sl * 8];
      }
#pragma unroll
      for (int nb = 0; nb < 4; ++nb) {
        int row = wn * 64 + nb * 16 + (l & 15);
        int sl = ((l >> 4) + kh * 4) ^ (row & 7);
        bfr[nb] = *(const bf16x8*)&lb[row * 64 + sl * 8];
      }
      __builtin_amdgcn_s_setprio(1);
#pragma unroll
      for (int mb = 0; mb < 4; ++mb)
#pragma unroll
        for (int nb = 0; nb < 4; ++nb)
          acc[mb][nb] = MFMA16(af[mb], bfr[nb], acc[mb][nb]);
      __builtin_amdgcn_s_setprio(0);
    }
  };

  // prologue: tile0 fully staged, tile1's A-DMA in flight
  load_B();                 // B(0) -> fb            FIFO: [B0x32]
  stage_A(0);               // A(0) -> buf0          FIFO: [B0, A0x2]
  stage_A(1);               // A(1) -> buf1          FIFO: [B0, A0, A1x2]
  VMCNT2();                 // B0 + A0 done; A1 in flight
  write_B(0);               // tile0 B -> buf0

  // CSTEP(b): t%3==b; stage A(t+2)->buf (b+2)%3; write B(t+1)->buf (b+1)%3
#define CSTEP(B0_, B1_, B2_)          \
  do {                                \
    LGKM0();                          \
    BARRIER();                        \
    load_B();                         \
    stage_A(B2_);                     \
    compute(B0_);                     \
    VMCNT2();                         \
    write_B(B1_);                     \
  } while (0)

  for (int it = 0; it < 42; ++it) {   // t = 0..125
    CSTEP(0, 1, 2);
    CSTEP(1, 2, 0);
    CSTEP(2, 0, 1);
  }
  // t = 126 (buf0): no A-stage (t+2 == 128)
  LGKM0();
  BARRIER();
  load_B();                 // B(127)
  compute(0);
  VMCNT0();                 // drain: B(127) + A(127) done
  write_B(1);               // tile127 -> buf1
  // t = 127 (buf1)
  LGKM0();
  BARRIER();
  compute(1);
#undef CSTEP

  // epilogue: D layout col=lane&15, row=(lane>>4)*4+reg (m89-verified)
#pragma unroll
  for (int mb = 0; mb < 4; ++mb)
#pragma unroll
    for (int nb = 0; nb < 4; ++nb)
#pragma unroll
      for (int r = 0; r < 4; ++r) {
        int rg = m0 + wm * 64 + mb * 16 + (l >> 4) * 4 + r;
        int cg = n0 + wn * 64 + nb * 16 + (l & 15);
        float vl = acc[mb][nb][r] * out_scale;
        if (WRITE_F32)
          ((float*)Cout)[(size_t)rg * DIMN + cg] = vl;
        else
          ((unsigned short*)Cout)[(size_t)rg * DIMN + cg] = f2bf(vl);
      }
}

// ---------------- fused flash attention (unchanged) ----------------
__global__ __launch_bounds__(256) void attn_kernel(
    const unsigned short* __restrict__ q, const unsigned short* __restrict__ k,
    const unsigned short* __restrict__ v, unsigned short* __restrict__ o) {
  __shared__ unsigned short Qs[64 * 72];
  __shared__ unsigned short Ks[64 * 72];
  __shared__ unsigned short Vt[64 * 72];
  __shared__ unsigned short Ps[4][16 * 72];

  const int t = threadIdx.x, l = t & 63, w = t >> 6;
  const int h = blockIdx.x >> 4;
  const int q0 = (blockIdx.x & 15) * 64;
  const int skey = t >> 2;
  const int sd = (t & 3) * 16;

  {
    const unsigned short* src = q + (size_t)(q0 + skey) * DIMN + h * 64 + sd;
    uint4 a = *(const uint4*)src;
    uint4 b = *(const uint4*)(src + 8);
    *(uint4*)&Qs[skey * 72 + sd] = a;
    *(uint4*)&Qs[skey * 72 + sd + 8] = b;
  }
  __syncthreads();
  bf16x8 qf[2];
#pragma unroll
  for (int kh = 0; kh < 2; ++kh)
    qf[kh] = *(const bf16x8*)&Qs[(w * 16 + (l & 15)) * 72 + (l >> 4) * 8 + kh * 32];

  float m_run[4] = {-1e30f, -1e30f, -1e30f, -1e30f};
  float l_run[4] = {0.f, 0.f, 0.f, 0.f};
  f32x4 oacc[4];
#pragma unroll
  for (int db = 0; db < 4; ++db) oacc[db] = (f32x4){0.f, 0.f, 0.f, 0.f};

  for (int kv = 0; kv < 16; ++kv) {
    __syncthreads();
    {
      const unsigned short* ksrc = k + (size_t)(kv * 64 + skey) * DIMN + h * 64 + sd;
      uint4 a = *(const uint4*)ksrc;
      uint4 b = *(const uint4*)(ksrc + 8);
      *(uint4*)&Ks[skey * 72 + sd] = a;
      *(uint4*)&Ks[skey * 72 + sd + 8] = b;
      const unsigned short* vsrc = v + (size_t)(kv * 64 + skey) * DIMN + h * 64 + sd;
      uint4 c = *(const uint4*)vsrc;
      uint4 d = *(const uint4*)(vsrc + 8);
      const unsigned short* cs = (const unsigned short*)&c;
      const unsigned short* ds = (const unsigned short*)&d;
#pragma unroll
      for (int j = 0; j < 8; ++j) Vt[(sd + j) * 72 + skey] = cs[j];
#pragma unroll
      for (int j = 0; j < 8; ++j) Vt[(sd + 8 + j) * 72 + skey] = ds[j];
    }
    __syncthreads();

    f32x4 sAcc[4];
#pragma unroll
    for (int nb = 0; nb < 4; ++nb) sAcc[nb] = (f32x4){0.f, 0.f, 0.f, 0.f};
#pragma unroll
    for (int kh = 0; kh < 2; ++kh) {
#pragma unroll
      for (int nb = 0; nb < 4; ++nb) {
        bf16x8 kf = *(const bf16x8*)&Ks[(nb * 16 + (l & 15)) * 72 + (l >> 4) * 8 + kh * 32];
        sAcc[nb] = MFMA16(qf[kh], kf, sAcc[nb]);
      }
    }

    float sc[4], mx[4];
#pragma unroll
    for (int r = 0; r < 4; ++r) {
      float mv = fmaxf(fmaxf(sAcc[0][r], sAcc[1][r]), fmaxf(sAcc[2][r], sAcc[3][r]));
      mv = fmaxf(mv, __shfl_xor(mv, 1));
      mv = fmaxf(mv, __shfl_xor(mv, 2));
      mv = fmaxf(mv, __shfl_xor(mv, 4));
      mv = fmaxf(mv, __shfl_xor(mv, 8));
      float mn = fmaxf(m_run[r], mv);
      sc[r] = __expf(m_run[r] - mn);
      m_run[r] = mn;
      mx[r] = mn;
    }
#pragma unroll
    for (int nb = 0; nb < 4; ++nb) {
      f32x4 sv = sAcc[nb];
#pragma unroll
      for (int r = 0; r < 4; ++r) sv[r] = __expf(sv[r] - mx[r]);
      sAcc[nb] = sv;
    }
#pragma unroll
    for (int r = 0; r < 4; ++r) {
      float ls = sAcc[0][r] + sAcc[1][r] + sAcc[2][r] + sAcc[3][r];
      ls += __shfl_xor(ls, 1);
      ls += __shfl_xor(ls, 2);
      ls += __shfl_xor(ls, 4);
      ls += __shfl_xor(ls, 8);
      l_run[r] = l_run[r] * sc[r] + ls;
    }
#pragma unroll
    for (int db = 0; db < 4; ++db) {
      f32x4 ov = oacc[db];
#pragma unroll
      for (int r = 0; r < 4; ++r) ov[r] *= sc[r];
      oacc[db] = ov;
    }

#pragma unroll
    for (int nb = 0; nb < 4; ++nb)
#pragma unroll
      for (int r = 0; r < 4; ++r)
        Ps[w][((l >> 4) * 4 + r) * 72 + nb * 16 + (l & 15)] = f2bf(sAcc[nb][r]);

#pragma unroll
    for (int kh = 0; kh < 2; ++kh) {
      bf16x8 pf = *(const bf16x8*)&Ps[w][(l & 15) * 72 + (l >> 4) * 8 + kh * 32];
#pragma unroll
      for (int db = 0; db < 4; ++db) {
        bf16x8 vf = *(const bf16x8*)&Vt[(db * 16 + (l & 15)) * 72 + (l >> 4) * 8 + kh * 32];
        oacc[db] = MFMA16(pf, vf, oacc[db]);
      }
    }
  }

#pragma unroll
  for (int db = 0; db < 4; ++db)
#pragma unroll
    for (int r = 0; r < 4; ++r) {
      float vl = oacc[db][r] / l_run[r];
      int rg = q0 + w * 16 + (l >> 4) * 4 + r;
      int cg = h * 64 + db * 16 + (l & 15);
      o[(size_t)rg * DIMN + cg] = f2bf(vl);
    }
}

extern "C" void kernel_launch(void* const* d_in, const int* in_sizes, int n_in,
                              void* d_out, int out_size, void* d_ws, size_t ws_size,
                              hipStream_t stream) {
  const float* x  = (const float*)d_in[0];
  const float* wq = (const float*)d_in[1];
  const float* wk = (const float*)d_in[2];
  const float* wv = (const float*)d_in[3];
  const float* wo = (const float*)d_in[4];

  char* ws = (char*)d_ws;
  const size_t MB16 = (size_t)16 * 1024 * 1024;
  unsigned short* xb = (unsigned short*)(ws);
  unsigned short* qb = (unsigned short*)(ws + 1 * MB16);
  unsigned short* kb = (unsigned short*)(ws + 2 * MB16);
  unsigned short* vb = (unsigned short*)(ws + 3 * MB16);
  unsigned short* ab = (unsigned short*)(ws + 4 * MB16);

  cvt_bf16_kernel<<<4096, 256, 0, stream>>>(x, xb);
  gemm_bf16<0><<<256, 512, 0, stream>>>(xb, wq, qb, 0.125f);  // softmax scale folded
  gemm_bf16<0><<<256, 512, 0, stream>>>(xb, wk, kb, 1.0f);
  gemm_bf16<0><<<256, 512, 0, stream>>>(xb, wv, vb, 1.0f);
  attn_kernel<<<2048, 256, 0, stream>>>(qb, kb, vb, ab);
  gemm_bf16<1><<<256, 512, 0, stream>>>(ab, wo, d_out, 1.0f);
}